// Round 1
// baseline (2019.512 us; speedup 1.0000x reference)
//
#include <hip/hip_runtime.h>
#include <math.h>

#define BQ 1024
#define NCAND 40000
#define NF 16
#define NFREQ 32
#define DEMB 48
#define DIN 784      // 16*48+16
#define DIM 512
#define NCLS 10
#define NCHUNK 8
#define HALF_SPAN 2500
#define ROWS_TOT (BQ + NCAND)
#define TWO_PI 6.28318530717958647692f

#define RT 16

__global__ __launch_bounds__(256)
void k_encode(const float* __restrict__ xq_num, const float* __restrict__ xq_cat,
              const float* __restrict__ xc_num, const float* __restrict__ xc_cat,
              const float* __restrict__ freq, const float* __restrict__ lin_w,
              const float* __restrict__ lin_b, const float* __restrict__ enc_w,
              const float* __restrict__ enc_b, float* __restrict__ h)
{
  __shared__ float a_s[RT][DIN];
  __shared__ float lin_s[64][DEMB];
  __shared__ float linb_s[DEMB];
  __shared__ float freq_s[NF * NFREQ];
  __shared__ float x_s[RT * NF];

  const int t = threadIdx.x;
  const long row0 = (long)blockIdx.x * RT;
  const bool isq = (row0 < BQ);
  const float* __restrict__ xnum = isq ? xq_num : xc_num;
  const float* __restrict__ xcat = isq ? xq_cat : xc_cat;
  const long rbase = isq ? row0 : (row0 - BQ);

  freq_s[t] = freq[t];
  freq_s[t + 256] = freq[t + 256];
  for (int i = t; i < 64 * DEMB; i += 256) ((float*)lin_s)[i] = lin_w[i];
  if (t < DEMB) linb_s[t] = lin_b[t];
  x_s[t] = xnum[rbase * NF + t];
  {
    const int r = t >> 4, i = t & 15;
    a_s[r][768 + i] = xcat[(rbase + r) * NF + i];
  }
  __syncthreads();

  // phase 1: one (row, field) per thread -> 48 emb values
  {
    const int r = t >> 4, f = t & 15;
    const float xv = x_s[r * NF + f];
    float feat[64];
#pragma unroll
    for (int k = 0; k < NFREQ; ++k) {
      float sv, cv;
      sincosf(TWO_PI * freq_s[f * NFREQ + k] * xv, &sv, &cv);
      feat[k] = cv;          // cos half
      feat[NFREQ + k] = sv;  // sin half
    }
    for (int j = 0; j < DEMB; ++j) {
      float s = linb_s[j];
#pragma unroll
      for (int k = 0; k < 64; ++k) s = fmaf(feat[k], lin_s[k][j], s);
      a_s[r][f * DEMB + j] = fmaxf(s, 0.f);
    }
  }
  __syncthreads();

  // phase 2: [16 x 784] @ [784 x 512], thread owns cols d0,d1 for all 16 rows
  const int d0 = t, d1 = t + 256;
  float acc0[RT], acc1[RT];
#pragma unroll
  for (int r = 0; r < RT; ++r) { acc0[r] = 0.f; acc1[r] = 0.f; }

  for (int i0 = 0; i0 < DIN; i0 += 4) {
    const float w00 = enc_w[(i0 + 0) * DIM + d0], w01 = enc_w[(i0 + 0) * DIM + d1];
    const float w10 = enc_w[(i0 + 1) * DIM + d0], w11 = enc_w[(i0 + 1) * DIM + d1];
    const float w20 = enc_w[(i0 + 2) * DIM + d0], w21 = enc_w[(i0 + 2) * DIM + d1];
    const float w30 = enc_w[(i0 + 3) * DIM + d0], w31 = enc_w[(i0 + 3) * DIM + d1];
#pragma unroll
    for (int r = 0; r < RT; ++r) {
      const float4 av = *(const float4*)&a_s[r][i0];
      float a0 = acc0[r], a1 = acc1[r];
      a0 = fmaf(av.x, w00, a0); a1 = fmaf(av.x, w01, a1);
      a0 = fmaf(av.y, w10, a0); a1 = fmaf(av.y, w11, a1);
      a0 = fmaf(av.z, w20, a0); a1 = fmaf(av.z, w21, a1);
      a0 = fmaf(av.w, w30, a0); a1 = fmaf(av.w, w31, a1);
      acc0[r] = a0; acc1[r] = a1;
    }
  }
  const float eb0 = enc_b[d0], eb1 = enc_b[d1];
#pragma unroll
  for (int r = 0; r < RT; ++r) {
    h[(row0 + r) * DIM + d0] = acc0[r] + eb0;
    h[(row0 + r) * DIM + d1] = acc1[r] + eb1;
  }
}

__global__ __launch_bounds__(256)
void k_norm(const float* __restrict__ h, float* __restrict__ norms)
{
  const int wid = blockIdx.x * 4 + (threadIdx.x >> 6);
  const int lane = threadIdx.x & 63;
  if (wid >= ROWS_TOT) return;
  const float* __restrict__ hr = h + (long)wid * DIM;
  float s = 0.f;
  for (int i = lane; i < DIM; i += 64) { const float v = hr[i]; s = fmaf(v, v, s); }
#pragma unroll
  for (int off = 32; off > 0; off >>= 1) s += __shfl_down(s, off, 64);
  if (lane == 0) norms[wid] = s;
}

// 32 query rows x 2500 candidates per block; fused distance/exp/reductions.
__global__ __launch_bounds__(256)
void k_dist(const float* __restrict__ h, const float* __restrict__ norms,
            const int* __restrict__ cand_y, float* __restrict__ cls_g,
            float* __restrict__ lse_g)
{
  __shared__ float q_s[32][16];
  __shared__ float c_s[256][20];   // pad to 20 floats: ~4-way instead of 32-way
  __shared__ float cls_s[32][NCLS];
  __shared__ float lse_s[32];
  __shared__ float qn_s[32];

  const int t = threadIdx.x;
  const int bg = t >> 5;      // 0..7 -> 4 query rows each
  const int jg = t & 31;      // 0..31 -> 8 candidates each (stride 32)
  const int b0 = blockIdx.y * 32;
  const int j0 = blockIdx.x * HALF_SPAN;   // candidate base index
  const int chunk = blockIdx.x >> 1;

  for (int i = t; i < 32 * NCLS; i += 256) ((float*)cls_s)[i] = 0.f;
  if (t < 32) { lse_s[t] = 0.f; qn_s[t] = norms[b0 + t]; }

  for (int jt = 0; jt < HALF_SPAN; jt += 256) {
    float acc[4][8];
#pragma unroll
    for (int r = 0; r < 4; ++r)
#pragma unroll
      for (int jc = 0; jc < 8; ++jc) acc[r][jc] = 0.f;

    for (int kt = 0; kt < DIM / 16; ++kt) {
      __syncthreads();
      {
        int e = t;
        q_s[e >> 4][e & 15] = h[(long)(b0 + (e >> 4)) * DIM + kt * 16 + (e & 15)];
        e = t + 256;
        q_s[e >> 4][e & 15] = h[(long)(b0 + (e >> 4)) * DIM + kt * 16 + (e & 15)];
      }
      {
        const int jr = jt + t;
        float4* dst = (float4*)&c_s[t][0];
        if (jr < HALF_SPAN) {
          const float4* src = (const float4*)&h[((long)(BQ + j0 + jr)) * DIM + kt * 16];
          dst[0] = src[0]; dst[1] = src[1]; dst[2] = src[2]; dst[3] = src[3];
        } else {
          const float4 z = {0.f, 0.f, 0.f, 0.f};
          dst[0] = z; dst[1] = z; dst[2] = z; dst[3] = z;
        }
      }
      __syncthreads();
#pragma unroll
      for (int kk = 0; kk < 16; kk += 4) {
        float4 qv[4];
#pragma unroll
        for (int r = 0; r < 4; ++r) qv[r] = *(const float4*)&q_s[bg * 4 + r][kk];
#pragma unroll
        for (int jc = 0; jc < 8; ++jc) {
          const float4 cv = *(const float4*)&c_s[jg + 32 * jc][kk];
#pragma unroll
          for (int r = 0; r < 4; ++r) {
            float a = acc[r][jc];
            a = fmaf(qv[r].x, cv.x, a);
            a = fmaf(qv[r].y, cv.y, a);
            a = fmaf(qv[r].z, cv.z, a);
            a = fmaf(qv[r].w, cv.w, a);
            acc[r][jc] = a;
          }
        }
      }
    }
    // epilogue: exp(-dist), class sums, sum of exp(exp_d)
#pragma unroll
    for (int r = 0; r < 4; ++r) {
      const int bl = bg * 4 + r;
      float ls = 0.f;
#pragma unroll
      for (int jc = 0; jc < 8; ++jc) {
        const int jr = jt + jg + 32 * jc;
        if (jr < HALF_SPAN) {
          const int jabs = j0 + jr;
          const float d2 = qn_s[bl] + norms[BQ + jabs] - 2.f * acc[r][jc];
          const float dist = sqrtf(fmaxf(d2, 1e-12f));
          const float e = expf(-dist);
          atomicAdd(&cls_s[bl][cand_y[jabs]], e);
          ls += expf(e);
        }
      }
      atomicAdd(&lse_s[bl], ls);
    }
  }
  __syncthreads();
  if (t < 32) atomicAdd(&lse_g[(b0 + t) * NCHUNK + chunk], lse_s[t]);
  for (int i = t; i < 32 * NCLS; i += 256)
    atomicAdd(&cls_g[(b0 + i / NCLS) * NCLS + (i % NCLS)], ((float*)cls_s)[i]);
}

__global__ __launch_bounds__(256)
void k_final(const float* __restrict__ cls_g, const float* __restrict__ lse_g,
             float* __restrict__ out)
{
  const int idx = blockIdx.x * 256 + threadIdx.x;
  if (idx >= BQ * NCLS) return;
  const int b = idx / NCLS;
  float lse = 0.f;
#pragma unroll
  for (int ch = 0; ch < NCHUNK; ++ch) lse += logf(lse_g[b * NCHUNK + ch]);
  out[idx] = logf(cls_g[idx]) - lse;
}

extern "C" void kernel_launch(void* const* d_in, const int* in_sizes, int n_in,
                              void* d_out, int out_size, void* d_ws, size_t ws_size,
                              hipStream_t stream)
{
  const float* xq_num = (const float*)d_in[0];
  const float* xq_cat = (const float*)d_in[1];
  // d_in[2] = y (unused by the reference output)
  const float* xc_num = (const float*)d_in[3];
  const float* xc_cat = (const float*)d_in[4];
  const int* cand_y = (const int*)d_in[5];
  const float* freq = (const float*)d_in[6];
  const float* lin_w = (const float*)d_in[7];
  const float* lin_b = (const float*)d_in[8];
  const float* enc_w = (const float*)d_in[9];
  const float* enc_b = (const float*)d_in[10];

  float* ws = (float*)d_ws;
  float* h = ws;                                   // [41024][512]
  float* norms = ws + (long)ROWS_TOT * DIM;        // [41024]
  float* cls_g = norms + ROWS_TOT;                 // [1024][10]
  float* lse_g = cls_g + BQ * NCLS;                // [1024][8]
  float* out = (float*)d_out;

  // zero global accumulators every call (graph-replay safe)
  hipMemsetAsync(cls_g, 0, (size_t)(BQ * NCLS + BQ * NCHUNK) * sizeof(float), stream);

  hipLaunchKernelGGL(k_encode, dim3(ROWS_TOT / RT), dim3(256), 0, stream,
                     xq_num, xq_cat, xc_num, xc_cat, freq, lin_w, lin_b,
                     enc_w, enc_b, h);
  hipLaunchKernelGGL(k_norm, dim3(ROWS_TOT / 4), dim3(256), 0, stream, h, norms);
  hipLaunchKernelGGL(k_dist, dim3(16, BQ / 32), dim3(256), 0, stream,
                     h, norms, cand_y, cls_g, lse_g);
  hipLaunchKernelGGL(k_final, dim3((BQ * NCLS + 255) / 256), dim3(256), 0, stream,
                     cls_g, lse_g, out);
}

// Round 2
// 416.525 us; speedup vs baseline: 4.8485x; 4.8485x over previous
//
#include <hip/hip_runtime.h>
#include <math.h>

typedef __attribute__((ext_vector_type(8))) short bf16x8;
typedef __attribute__((ext_vector_type(4))) float f32x4;
typedef unsigned short u16;
typedef unsigned int u32;

#define BQ 1024
#define NCAND 40000
#define ROWS_TOT 41024
#define NF 16
#define NFREQ 32
#define DEMB 48
#define KDIM 800          // 784 padded to 800 (K % 32 == 0)
#define ASTRIDE 808       // LDS row stride in bf16 (odd*8 -> 2-way bank alias = free)
#define DIM 512
#define NCLS 10
#define NCHUNK 8
#define CHUNKSZ 5000
#define CT_PER_CHUNK 40   // ceil(5000/128)
#define NCT 320           // 8 chunks * 40 tiles
#define TWO_PI 6.28318530717958647692f

__device__ __forceinline__ u16 f2bf(float f) {
  u32 u = __float_as_uint(f);
  u32 r = u + 0x7fffu + ((u >> 16) & 1u);  // RNE
  return (u16)(r >> 16);
}
__device__ __forceinline__ float bf2f(u16 b) { return __uint_as_float(((u32)b) << 16); }

// ---- convert enc_w [784][512] f32 -> enc_wT [512][800] bf16 (zero-padded K) ----
__global__ __launch_bounds__(256)
void k_prep(const float* __restrict__ enc_w, u16* __restrict__ enc_wT)
{
  int idx = blockIdx.x * 256 + threadIdx.x;
  if (idx >= DIM * KDIM) return;
  int n = idx / KDIM, k = idx - n * KDIM;
  u16 v = 0;
  if (k < 784) v = f2bf(enc_w[k * DIM + n]);
  enc_wT[idx] = v;
}

// ---- PLR encode + [32 x 800] @ [800 x 512] bf16 MFMA + fused norms ----
__global__ __launch_bounds__(256)
void k_encode(const float* __restrict__ xq_num, const float* __restrict__ xq_cat,
              const float* __restrict__ xc_num, const float* __restrict__ xc_cat,
              const float* __restrict__ freq, const float* __restrict__ lin_w,
              const float* __restrict__ lin_b, const u16* __restrict__ enc_wT,
              const float* __restrict__ enc_b,
              u16* __restrict__ h_bf, float* __restrict__ norms)
{
  __shared__ u16 a_s[32 * ASTRIDE];        // 51.7 KB
  __shared__ float lin_s[64 * DEMB];       // 12 KB
  __shared__ float linb_s[DEMB];
  __shared__ float norm_s[32];

  const int t = threadIdx.x;
  const int row0 = blockIdx.x * 32;
  const bool isq = (row0 < BQ);
  const float* __restrict__ xnum = isq ? xq_num : xc_num;
  const float* __restrict__ xcat = isq ? xq_cat : xc_cat;
  const int rbase = isq ? row0 : (row0 - BQ);

  for (int i = t; i < 64 * DEMB; i += 256) lin_s[i] = lin_w[i];
  if (t < DEMB) linb_s[t] = lin_b[t];
  if (t < 32) norm_s[t] = 0.f;
  // cat features -> cols 768..783
  for (int i = t; i < 32 * 16; i += 256) {
    int r = i >> 4, c = i & 15;
    a_s[r * ASTRIDE + 768 + c] = f2bf(xcat[(rbase + r) * NF + c]);
  }
  // zero pad cols 784..807
  for (int i = t; i < 32 * 24; i += 256) {
    int r = i / 24, c = i - r * 24;
    a_s[r * ASTRIDE + 784 + c] = 0;
  }
  __syncthreads();

  // phase 1: (row, field) tasks; 512 tasks over 256 threads
  for (int tk = t; tk < 512; tk += 256) {
    int r = tk >> 4, f = tk & 15;
    float xv = xnum[(rbase + r) * NF + f];
    float feat[64];
#pragma unroll
    for (int k = 0; k < NFREQ; ++k) {
      float tt = TWO_PI * freq[f * NFREQ + k] * xv;
      feat[k] = __cosf(tt);
      feat[NFREQ + k] = __sinf(tt);
    }
    for (int j = 0; j < DEMB; ++j) {
      float s = linb_s[j];
#pragma unroll
      for (int k = 0; k < 64; ++k) s = fmaf(feat[k], lin_s[k * DEMB + j], s);
      a_s[r * ASTRIDE + f * DEMB + j] = f2bf(fmaxf(s, 0.f));
    }
  }
  __syncthreads();

  // phase 2: MFMA. 4 waves, wave owns 128 output cols. frags: 2(M) x 8(N).
  const int wid = t >> 6, l = t & 63, hi = l >> 4, lo = l & 15;
  f32x4 acc[2][8];
#pragma unroll
  for (int mf = 0; mf < 2; ++mf)
#pragma unroll
    for (int nf = 0; nf < 8; ++nf) acc[mf][nf] = 0.f;

  for (int kt = 0; kt < KDIM / 32; ++kt) {
    bf16x8 af[2], bw[8];
#pragma unroll
    for (int mf = 0; mf < 2; ++mf)
      af[mf] = *(const bf16x8*)&a_s[(mf * 16 + lo) * ASTRIDE + kt * 32 + hi * 8];
#pragma unroll
    for (int nf = 0; nf < 8; ++nf)
      bw[nf] = *(const bf16x8*)&enc_wT[(size_t)(wid * 128 + nf * 16 + lo) * KDIM + kt * 32 + hi * 8];
#pragma unroll
    for (int mf = 0; mf < 2; ++mf)
#pragma unroll
      for (int nf = 0; nf < 8; ++nf)
        acc[mf][nf] = __builtin_amdgcn_mfma_f32_16x16x32_bf16(af[mf], bw[nf], acc[mf][nf], 0, 0, 0);
  }

  // epilogue: bias, bf16 store, norm accumulation
  float encb_v[8];
#pragma unroll
  for (int nf = 0; nf < 8; ++nf) encb_v[nf] = enc_b[wid * 128 + nf * 16 + lo];
  float nacc[2][4];
#pragma unroll
  for (int mf = 0; mf < 2; ++mf)
#pragma unroll
    for (int r = 0; r < 4; ++r) nacc[mf][r] = 0.f;

#pragma unroll
  for (int mf = 0; mf < 2; ++mf)
#pragma unroll
    for (int nf = 0; nf < 8; ++nf)
#pragma unroll
      for (int r = 0; r < 4; ++r) {
        int m = mf * 16 + hi * 4 + r;
        int n = wid * 128 + nf * 16 + lo;
        float hv = acc[mf][nf][r] + encb_v[nf];
        u16 ub = f2bf(hv);
        h_bf[(size_t)(row0 + m) * DIM + n] = ub;
        float hb = bf2f(ub);
        nacc[mf][r] = fmaf(hb, hb, nacc[mf][r]);
      }
#pragma unroll
  for (int mf = 0; mf < 2; ++mf)
#pragma unroll
    for (int r = 0; r < 4; ++r) {
      float v = nacc[mf][r];
      v += __shfl_xor(v, 1); v += __shfl_xor(v, 2);
      v += __shfl_xor(v, 4); v += __shfl_xor(v, 8);
      if (lo == 0) atomicAdd(&norm_s[mf * 16 + hi * 4 + r], v);
    }
  __syncthreads();
  if (t < 32) norms[row0 + t] = norm_s[t];
}

// ---- fused distance MFMA + exp + class-bin/LSE partial reduction ----
// grid: (320 cand tiles chunk-aligned, 16 query tiles); block 256 (4 waves)
__global__ __launch_bounds__(256)
void k_dist(const u16* __restrict__ h_bf, const float* __restrict__ norms,
            const int* __restrict__ cand_y,
            float* __restrict__ cls_part, float* __restrict__ lse_part)
{
  __shared__ u16 A_s[128 * 64];      // cand tile, XOR-swizzled
  __shared__ u16 B_s[64 * 64];       // query tile, XOR-swizzled
  __shared__ float qn_s[64];
  __shared__ float cn_s[128];
  __shared__ int cy_s[128];
  __shared__ float red_s[64][11];    // per-query 10 class sums + lse partial

  const int t = threadIdx.x;
  const int bx = blockIdx.x;
  const int chunk = bx / CT_PER_CHUNK;
  const int ctl = bx - chunk * CT_PER_CHUNK;
  const int cand0 = chunk * CHUNKSZ + ctl * 128;
  const int cend = chunk * CHUNKSZ + CHUNKSZ;
  const int q0 = blockIdx.y * 64;

  for (int i = t; i < 64 * 11; i += 256) ((float*)red_s)[i] = 0.f;
  if (t < 64) qn_s[t] = norms[q0 + t];
  if (t < 128) {
    int j = cand0 + t; if (j > cend - 1) j = cend - 1;
    cn_s[t] = norms[BQ + j];
    cy_s[t] = cand_y[j];
  }

  const int wid = t >> 6, l = t & 63, hi = l >> 4, lo = l & 15;
  const int wm = wid & 1, wn = wid >> 1;   // wave tile: 64 cand x 32 query

  f32x4 acc[4][2];
#pragma unroll
  for (int mi = 0; mi < 4; ++mi)
#pragma unroll
    for (int ni = 0; ni < 2; ++ni) acc[mi][ni] = 0.f;

  for (int kt = 0; kt < DIM / 64; ++kt) {
    __syncthreads();
#pragma unroll
    for (int p = 0; p < 4; ++p) {        // A tile: 128 rows x 64 bf16
      int idx = p * 256 + t;
      int lrow = idx >> 3, slot = idx & 7;
      int crow = cand0 + lrow; if (crow > cend - 1) crow = cend - 1;
      float4 v = *(const float4*)&h_bf[(size_t)(BQ + crow) * DIM + kt * 64 + slot * 8];
      *(float4*)&A_s[lrow * 64 + ((((u32)slot * 16) ^ (((u32)lrow & 7) << 4)) >> 1)] = v;
    }
#pragma unroll
    for (int p = 0; p < 2; ++p) {        // B tile: 64 rows x 64 bf16
      int idx = p * 256 + t;
      int qrow = idx >> 3, slot = idx & 7;
      float4 v = *(const float4*)&h_bf[(size_t)(q0 + qrow) * DIM + kt * 64 + slot * 8];
      *(float4*)&B_s[qrow * 64 + ((((u32)slot * 16) ^ (((u32)qrow & 7) << 4)) >> 1)] = v;
    }
    __syncthreads();
#pragma unroll
    for (int ks = 0; ks < 2; ++ks) {
      bf16x8 af[4], bq[2];
#pragma unroll
      for (int mi = 0; mi < 4; ++mi) {
        int row = wm * 64 + mi * 16 + lo;
        int byt = (hi * 16 + ks * 64) ^ ((row & 7) << 4);
        af[mi] = *(const bf16x8*)&A_s[row * 64 + (byt >> 1)];
      }
#pragma unroll
      for (int ni = 0; ni < 2; ++ni) {
        int row = wn * 32 + ni * 16 + lo;
        int byt = (hi * 16 + ks * 64) ^ ((row & 7) << 4);
        bq[ni] = *(const bf16x8*)&B_s[row * 64 + (byt >> 1)];
      }
#pragma unroll
      for (int mi = 0; mi < 4; ++mi)
#pragma unroll
        for (int ni = 0; ni < 2; ++ni)
          acc[mi][ni] = __builtin_amdgcn_mfma_f32_16x16x32_bf16(af[mi], bq[ni], acc[mi][ni], 0, 0, 0);
    }
  }

  // epilogue: d2 -> dist -> e; register class bins (static idx) + lse partial
  float cacc[2][NCLS], lacc[2];
#pragma unroll
  for (int ni = 0; ni < 2; ++ni) {
    lacc[ni] = 0.f;
#pragma unroll
    for (int c = 0; c < NCLS; ++c) cacc[ni][c] = 0.f;
  }
#pragma unroll
  for (int mi = 0; mi < 4; ++mi)
#pragma unroll
    for (int r = 0; r < 4; ++r) {
      int crow = wm * 64 + mi * 16 + hi * 4 + r;
      int jabs = cand0 + crow;
      bool valid = jabs < cend;
      float cn = cn_s[crow];
      int y = cy_s[crow];
#pragma unroll
      for (int ni = 0; ni < 2; ++ni) {
        float qn = qn_s[wn * 32 + ni * 16 + lo];
        float a = acc[mi][ni][r];
        float d2 = cn + qn - 2.f * a;
        float dist = sqrtf(fmaxf(d2, 1e-12f));
        float e = valid ? __expf(-dist) : 0.f;
        lacc[ni] += valid ? __expf(e) : 0.f;
#pragma unroll
        for (int c = 0; c < NCLS; ++c) cacc[ni][c] += (y == c) ? e : 0.f;
      }
    }

  // reduce across the 4 sixteen-lane groups, then across waves via LDS
#pragma unroll
  for (int ni = 0; ni < 2; ++ni) {
    float v = lacc[ni];
    v += __shfl_xor(v, 16); v += __shfl_xor(v, 32);
#pragma unroll
    for (int c = 0; c < NCLS; ++c) {
      float w = cacc[ni][c];
      w += __shfl_xor(w, 16); w += __shfl_xor(w, 32);
      cacc[ni][c] = w;
    }
    if (hi == 0) {
      int q = wn * 32 + ni * 16 + lo;
      atomicAdd(&red_s[q][10], v);
#pragma unroll
      for (int c = 0; c < NCLS; ++c) atomicAdd(&red_s[q][c], cacc[ni][c]);
    }
  }
  __syncthreads();

  for (int i = t; i < 64 * NCLS; i += 256) {
    int q = i / NCLS, c = i - q * NCLS;
    cls_part[((size_t)bx * BQ + (q0 + q)) * NCLS + c] = red_s[q][c];
  }
  if (t < 64) lse_part[(size_t)bx * BQ + q0 + t] = red_s[t][10];
}

// ---- combine partials: out = log(cls) - sum_chunk log(lse_chunk) ----
__global__ __launch_bounds__(320)
void k_final(const float* __restrict__ cls_part, const float* __restrict__ lse_part,
             float* __restrict__ out)
{
  __shared__ float cls_sum[NCLS];
  __shared__ float ch_sum[NCHUNK];
  const int t = threadIdx.x;   // 0..319 = cand tile
  const int b = blockIdx.x;
  if (t < NCLS) cls_sum[t] = 0.f;
  if (t < NCHUNK) ch_sum[t] = 0.f;
  __syncthreads();

  float cs[NCLS];
#pragma unroll
  for (int c = 0; c < NCLS; ++c) cs[c] = cls_part[((size_t)t * BQ + b) * NCLS + c];
  float ls = lse_part[(size_t)t * BQ + b];
  atomicAdd(&ch_sum[t / CT_PER_CHUNK], ls);
#pragma unroll
  for (int c = 0; c < NCLS; ++c) {
    float w = cs[c];
    w += __shfl_xor(w, 1); w += __shfl_xor(w, 2); w += __shfl_xor(w, 4);
    w += __shfl_xor(w, 8); w += __shfl_xor(w, 16); w += __shfl_xor(w, 32);
    if ((t & 63) == 0) atomicAdd(&cls_sum[c], w);
  }
  __syncthreads();
  if (t < NCLS) {
    float lse = 0.f;
#pragma unroll
    for (int ch = 0; ch < NCHUNK; ++ch) lse += logf(ch_sum[ch]);
    out[b * NCLS + t] = logf(cls_sum[t]) - lse;
  }
}

extern "C" void kernel_launch(void* const* d_in, const int* in_sizes, int n_in,
                              void* d_out, int out_size, void* d_ws, size_t ws_size,
                              hipStream_t stream)
{
  const float* xq_num = (const float*)d_in[0];
  const float* xq_cat = (const float*)d_in[1];
  // d_in[2] = y (unused)
  const float* xc_num = (const float*)d_in[3];
  const float* xc_cat = (const float*)d_in[4];
  const int* cand_y = (const int*)d_in[5];
  const float* freq = (const float*)d_in[6];
  const float* lin_w = (const float*)d_in[7];
  const float* lin_b = (const float*)d_in[8];
  const float* enc_w = (const float*)d_in[9];
  const float* enc_b = (const float*)d_in[10];

  u16* h_bf = (u16*)d_ws;                                        // 41024*512 bf16
  float* norms = (float*)((char*)d_ws + (size_t)ROWS_TOT * DIM * 2);
  float* cls_part = norms + ROWS_TOT;                            // [320][1024][10]
  float* lse_part = cls_part + (size_t)NCT * BQ * NCLS;          // [320][1024]
  u16* enc_wT = (u16*)(lse_part + (size_t)NCT * BQ);             // [512][800]
  float* out = (float*)d_out;

  hipLaunchKernelGGL(k_prep, dim3((DIM * KDIM + 255) / 256), dim3(256), 0, stream,
                     enc_w, enc_wT);
  hipLaunchKernelGGL(k_encode, dim3(ROWS_TOT / 32), dim3(256), 0, stream,
                     xq_num, xq_cat, xc_num, xc_cat, freq, lin_w, lin_b,
                     enc_wT, enc_b, h_bf, norms);
  hipLaunchKernelGGL(k_dist, dim3(NCT, BQ / 64), dim3(256), 0, stream,
                     h_bf, norms, cand_y, cls_part, lse_part);
  hipLaunchKernelGGL(k_final, dim3(BQ), dim3(320), 0, stream,
                     cls_part, lse_part, out);
}

// Round 3
// 237.982 us; speedup vs baseline: 8.4860x; 1.7502x over previous
//
#include <hip/hip_runtime.h>
#include <math.h>

typedef __attribute__((ext_vector_type(8))) short bf16x8;
typedef __attribute__((ext_vector_type(4))) float f32x4;
typedef unsigned short u16;
typedef unsigned int u32;

#define BQ 1024
#define NCAND 40000
#define ROWS_TOT 41024
#define NF 16
#define NFREQ 32
#define DEMB 48
#define KDIM 800          // 784 padded to 800 (K % 32 == 0)
#define ASTRIDE 808       // LDS row stride in bf16 (odd*8 -> 2-way bank alias = free)
#define DIM 512
#define NCLS 10
#define NCHUNK 8
#define CHUNKSZ 5000
#define CT_PER_CHUNK 40   // ceil(5000/128)
#define NCT 320           // 8 chunks * 40 tiles
#define TWO_PI 6.28318530717958647692f

__device__ __forceinline__ u16 f2bf(float f) {
  u32 u = __float_as_uint(f);
  u32 r = u + 0x7fffu + ((u >> 16) & 1u);  // RNE
  return (u16)(r >> 16);
}
__device__ __forceinline__ float bf2f(u16 b) { return __uint_as_float(((u32)b) << 16); }

// ---- convert enc_w [784][512] f32 -> enc_wT [512][800] bf16 (zero-padded K) ----
__global__ __launch_bounds__(256)
void k_prep(const float* __restrict__ enc_w, u16* __restrict__ enc_wT)
{
  int idx = blockIdx.x * 256 + threadIdx.x;
  if (idx >= DIM * KDIM) return;
  int n = idx / KDIM, k = idx - n * KDIM;
  u16 v = 0;
  if (k < 784) v = f2bf(enc_w[k * DIM + n]);
  enc_wT[idx] = v;
}

// ---- PLR encode (MFMA, in-register A-frags) + [32x800]@[800x512] MFMA + norms ----
__global__ __launch_bounds__(256, 3)
void k_encode(const float* __restrict__ xq_num, const float* __restrict__ xq_cat,
              const float* __restrict__ xc_num, const float* __restrict__ xc_cat,
              const float* __restrict__ freq, const float* __restrict__ lin_w,
              const float* __restrict__ lin_b, const u16* __restrict__ enc_wT,
              const float* __restrict__ enc_b,
              u16* __restrict__ h_bf, float* __restrict__ norms)
{
  __shared__ u16 a_s[32 * ASTRIDE];        // 51.7 KB
  __shared__ float norm_s[32];

  const int t = threadIdx.x;
  const int row0 = blockIdx.x * 32;
  const bool isq = (row0 < BQ);
  const float* __restrict__ xnum = isq ? xq_num : xc_num;
  const float* __restrict__ xcat = isq ? xq_cat : xc_cat;
  const int rbase = isq ? row0 : (row0 - BQ);

  const int wid = t >> 6, l = t & 63, hi = l >> 4, lo = l & 15;

  if (t < 32) norm_s[t] = 0.f;
  // cat features -> cols 768..783
  for (int i = t; i < 32 * 16; i += 256) {
    int r = i >> 4, c = i & 15;
    a_s[r * ASTRIDE + 768 + c] = f2bf(xcat[(rbase + r) * NF + c]);
  }
  // zero pad cols 784..807
  for (int i = t; i < 32 * 24; i += 256) {
    int r = i / 24, c = i - r * 24;
    a_s[r * ASTRIDE + 784 + c] = 0;
  }

  // ---- phase 1: emb = relu(feats @ lin_w + b) via MFMA, feats never touch LDS.
  // wave handles tasks wid*128 .. +127  (rows wid*8..+7, all 16 fields).
  // A-frag partition: lane(hi,lo) computes cos/sin(freq[lo][hi*8+e] * x[r][lo]).
  {
    float fq[8];
    *(float4*)&fq[0] = *(const float4*)&freq[lo * NFREQ + hi * 8];
    *(float4*)&fq[4] = *(const float4*)&freq[lo * NFREQ + hi * 8 + 4];
    float xv[8];
#pragma unroll
    for (int mi = 0; mi < 8; ++mi)
      xv[mi] = xnum[(rbase + wid * 8 + mi) * NF + lo];

    // B-frags: lin_w[64][48]; lane holds B[k=kf*32+hi*8+e][j=nf*16+lo]
    bf16x8 lwb[2][3];
#pragma unroll
    for (int kf = 0; kf < 2; ++kf)
#pragma unroll
      for (int nf = 0; nf < 3; ++nf)
#pragma unroll
        for (int e = 0; e < 8; ++e)
          lwb[kf][nf][e] = (short)f2bf(lin_w[(kf * 32 + hi * 8 + e) * DEMB + nf * 16 + lo]);
    float lb[3];
#pragma unroll
    for (int nf = 0; nf < 3; ++nf) lb[nf] = lin_b[nf * 16 + lo];

#pragma unroll
    for (int mi = 0; mi < 8; ++mi) {
      bf16x8 ac, as_;
#pragma unroll
      for (int e = 0; e < 8; ++e) {
        float tt = TWO_PI * fq[e] * xv[mi];
        ac[e] = (short)f2bf(__cosf(tt));
        as_[e] = (short)f2bf(__sinf(tt));
      }
#pragma unroll
      for (int nf = 0; nf < 3; ++nf) {
        f32x4 ec = {0.f, 0.f, 0.f, 0.f};
        ec = __builtin_amdgcn_mfma_f32_16x16x32_bf16(ac, lwb[0][nf], ec, 0, 0, 0);
        ec = __builtin_amdgcn_mfma_f32_16x16x32_bf16(as_, lwb[1][nf], ec, 0, 0, 0);
        // C: lane holds emb[task mi*16 + hi*4 + reg][j = nf*16 + lo]
#pragma unroll
        for (int reg = 0; reg < 4; ++reg) {
          int f = hi * 4 + reg;
          int r = wid * 8 + mi;
          float v = fmaxf(ec[reg] + lb[nf], 0.f);
          a_s[r * ASTRIDE + f * DEMB + nf * 16 + lo] = f2bf(v);
        }
      }
    }
  }
  __syncthreads();

  // ---- phase 2: [32 x 800] @ [800 x 512]; wave owns 128 output cols.
  f32x4 acc[2][8];
#pragma unroll
  for (int mf = 0; mf < 2; ++mf)
#pragma unroll
    for (int nf = 0; nf < 8; ++nf) acc[mf][nf] = 0.f;

  for (int kt = 0; kt < KDIM / 32; ++kt) {
    bf16x8 af[2], bw[8];
#pragma unroll
    for (int mf = 0; mf < 2; ++mf)
      af[mf] = *(const bf16x8*)&a_s[(mf * 16 + lo) * ASTRIDE + kt * 32 + hi * 8];
#pragma unroll
    for (int nf = 0; nf < 8; ++nf)
      bw[nf] = *(const bf16x8*)&enc_wT[(size_t)(wid * 128 + nf * 16 + lo) * KDIM + kt * 32 + hi * 8];
#pragma unroll
    for (int mf = 0; mf < 2; ++mf)
#pragma unroll
      for (int nf = 0; nf < 8; ++nf)
        acc[mf][nf] = __builtin_amdgcn_mfma_f32_16x16x32_bf16(af[mf], bw[nf], acc[mf][nf], 0, 0, 0);
  }

  // epilogue: bias, bf16 store, norm accumulation
  float encb_v[8];
#pragma unroll
  for (int nf = 0; nf < 8; ++nf) encb_v[nf] = enc_b[wid * 128 + nf * 16 + lo];
  float nacc[2][4];
#pragma unroll
  for (int mf = 0; mf < 2; ++mf)
#pragma unroll
    for (int r = 0; r < 4; ++r) nacc[mf][r] = 0.f;

#pragma unroll
  for (int mf = 0; mf < 2; ++mf)
#pragma unroll
    for (int nf = 0; nf < 8; ++nf)
#pragma unroll
      for (int r = 0; r < 4; ++r) {
        int m = mf * 16 + hi * 4 + r;
        int n = wid * 128 + nf * 16 + lo;
        float hv = acc[mf][nf][r] + encb_v[nf];
        u16 ub = f2bf(hv);
        h_bf[(size_t)(row0 + m) * DIM + n] = ub;
        float hb = bf2f(ub);
        nacc[mf][r] = fmaf(hb, hb, nacc[mf][r]);
      }
#pragma unroll
  for (int mf = 0; mf < 2; ++mf)
#pragma unroll
    for (int r = 0; r < 4; ++r) {
      float v = nacc[mf][r];
      v += __shfl_xor(v, 1); v += __shfl_xor(v, 2);
      v += __shfl_xor(v, 4); v += __shfl_xor(v, 8);
      if (lo == 0) atomicAdd(&norm_s[mf * 16 + hi * 4 + r], v);
    }
  __syncthreads();
  if (t < 32) norms[row0 + t] = norm_s[t];
}

// ---- fused distance MFMA + exp + class-bin/LSE partial reduction ----
// grid: (320 cand tiles chunk-aligned, 16 query tiles); block 256 (4 waves)
__global__ __launch_bounds__(256)
void k_dist(const u16* __restrict__ h_bf, const float* __restrict__ norms,
            const int* __restrict__ cand_y,
            float* __restrict__ cls_part, float* __restrict__ lse_part)
{
  __shared__ u16 A_s[128 * 64];      // cand tile, XOR-swizzled
  __shared__ u16 B_s[64 * 64];       // query tile, XOR-swizzled
  __shared__ float qn_s[64];
  __shared__ float cn_s[128];
  __shared__ int cy_s[128];
  __shared__ float red_s[64][11];    // per-query 10 class sums + lse partial

  const int t = threadIdx.x;
  const int bx = blockIdx.x;
  const int chunk = bx / CT_PER_CHUNK;
  const int ctl = bx - chunk * CT_PER_CHUNK;
  const int cand0 = chunk * CHUNKSZ + ctl * 128;
  const int cend = chunk * CHUNKSZ + CHUNKSZ;
  const int q0 = blockIdx.y * 64;

  for (int i = t; i < 64 * 11; i += 256) ((float*)red_s)[i] = 0.f;
  if (t < 64) qn_s[t] = norms[q0 + t];
  if (t < 128) {
    int j = cand0 + t; if (j > cend - 1) j = cend - 1;
    cn_s[t] = norms[BQ + j];
    cy_s[t] = cand_y[j];
  }

  const int wid = t >> 6, l = t & 63, hi = l >> 4, lo = l & 15;
  const int wm = wid & 1, wn = wid >> 1;   // wave tile: 64 cand x 32 query

  f32x4 acc[4][2];
#pragma unroll
  for (int mi = 0; mi < 4; ++mi)
#pragma unroll
    for (int ni = 0; ni < 2; ++ni) acc[mi][ni] = 0.f;

  for (int kt = 0; kt < DIM / 64; ++kt) {
    __syncthreads();
#pragma unroll
    for (int p = 0; p < 4; ++p) {        // A tile: 128 rows x 64 bf16
      int idx = p * 256 + t;
      int lrow = idx >> 3, slot = idx & 7;
      int crow = cand0 + lrow; if (crow > cend - 1) crow = cend - 1;
      float4 v = *(const float4*)&h_bf[(size_t)(BQ + crow) * DIM + kt * 64 + slot * 8];
      *(float4*)&A_s[lrow * 64 + ((((u32)slot * 16) ^ (((u32)lrow & 7) << 4)) >> 1)] = v;
    }
#pragma unroll
    for (int p = 0; p < 2; ++p) {        // B tile: 64 rows x 64 bf16
      int idx = p * 256 + t;
      int qrow = idx >> 3, slot = idx & 7;
      float4 v = *(const float4*)&h_bf[(size_t)(q0 + qrow) * DIM + kt * 64 + slot * 8];
      *(float4*)&B_s[qrow * 64 + ((((u32)slot * 16) ^ (((u32)qrow & 7) << 4)) >> 1)] = v;
    }
    __syncthreads();
#pragma unroll
    for (int ks = 0; ks < 2; ++ks) {
      bf16x8 af[4], bq[2];
#pragma unroll
      for (int mi = 0; mi < 4; ++mi) {
        int row = wm * 64 + mi * 16 + lo;
        int byt = (hi * 16 + ks * 64) ^ ((row & 7) << 4);
        af[mi] = *(const bf16x8*)&A_s[row * 64 + (byt >> 1)];
      }
#pragma unroll
      for (int ni = 0; ni < 2; ++ni) {
        int row = wn * 32 + ni * 16 + lo;
        int byt = (hi * 16 + ks * 64) ^ ((row & 7) << 4);
        bq[ni] = *(const bf16x8*)&B_s[row * 64 + (byt >> 1)];
      }
#pragma unroll
      for (int mi = 0; mi < 4; ++mi)
#pragma unroll
        for (int ni = 0; ni < 2; ++ni)
          acc[mi][ni] = __builtin_amdgcn_mfma_f32_16x16x32_bf16(af[mi], bq[ni], acc[mi][ni], 0, 0, 0);
    }
  }

  // epilogue: d2 -> dist -> e; register class bins (static idx) + lse partial
  float cacc[2][NCLS], lacc[2];
#pragma unroll
  for (int ni = 0; ni < 2; ++ni) {
    lacc[ni] = 0.f;
#pragma unroll
    for (int c = 0; c < NCLS; ++c) cacc[ni][c] = 0.f;
  }
#pragma unroll
  for (int mi = 0; mi < 4; ++mi)
#pragma unroll
    for (int r = 0; r < 4; ++r) {
      int crow = wm * 64 + mi * 16 + hi * 4 + r;
      int jabs = cand0 + crow;
      bool valid = jabs < cend;
      float cn = cn_s[crow];
      int y = cy_s[crow];
#pragma unroll
      for (int ni = 0; ni < 2; ++ni) {
        float qn = qn_s[wn * 32 + ni * 16 + lo];
        float a = acc[mi][ni][r];
        float d2 = cn + qn - 2.f * a;
        float dist = sqrtf(fmaxf(d2, 1e-12f));
        float e = valid ? __expf(-dist) : 0.f;
        lacc[ni] += valid ? __expf(e) : 0.f;
#pragma unroll
        for (int c = 0; c < NCLS; ++c) cacc[ni][c] += (y == c) ? e : 0.f;
      }
    }

  // reduce across the 4 sixteen-lane groups, then across waves via LDS
#pragma unroll
  for (int ni = 0; ni < 2; ++ni) {
    float v = lacc[ni];
    v += __shfl_xor(v, 16); v += __shfl_xor(v, 32);
#pragma unroll
    for (int c = 0; c < NCLS; ++c) {
      float w = cacc[ni][c];
      w += __shfl_xor(w, 16); w += __shfl_xor(w, 32);
      cacc[ni][c] = w;
    }
    if (hi == 0) {
      int q = wn * 32 + ni * 16 + lo;
      atomicAdd(&red_s[q][10], v);
#pragma unroll
      for (int c = 0; c < NCLS; ++c) atomicAdd(&red_s[q][c], cacc[ni][c]);
    }
  }
  __syncthreads();

  for (int i = t; i < 64 * NCLS; i += 256) {
    int q = i / NCLS, c = i - q * NCLS;
    cls_part[((size_t)bx * BQ + (q0 + q)) * NCLS + c] = red_s[q][c];
  }
  if (t < 64) lse_part[(size_t)bx * BQ + q0 + t] = red_s[t][10];
}

// ---- combine partials: out = log(cls) - sum_chunk log(lse_chunk) ----
__global__ __launch_bounds__(320)
void k_final(const float* __restrict__ cls_part, const float* __restrict__ lse_part,
             float* __restrict__ out)
{
  __shared__ float cls_sum[NCLS];
  __shared__ float ch_sum[NCHUNK];
  const int t = threadIdx.x;   // 0..319 = cand tile
  const int b = blockIdx.x;
  if (t < NCLS) cls_sum[t] = 0.f;
  if (t < NCHUNK) ch_sum[t] = 0.f;
  __syncthreads();

  float cs[NCLS];
#pragma unroll
  for (int c = 0; c < NCLS; ++c) cs[c] = cls_part[((size_t)t * BQ + b) * NCLS + c];
  float ls = lse_part[(size_t)t * BQ + b];
  atomicAdd(&ch_sum[t / CT_PER_CHUNK], ls);
#pragma unroll
  for (int c = 0; c < NCLS; ++c) {
    float w = cs[c];
    w += __shfl_xor(w, 1); w += __shfl_xor(w, 2); w += __shfl_xor(w, 4);
    w += __shfl_xor(w, 8); w += __shfl_xor(w, 16); w += __shfl_xor(w, 32);
    if ((t & 63) == 0) atomicAdd(&cls_sum[c], w);
  }
  __syncthreads();
  if (t < NCLS) {
    float lse = 0.f;
#pragma unroll
    for (int ch = 0; ch < NCHUNK; ++ch) lse += logf(ch_sum[ch]);
    out[b * NCLS + t] = logf(cls_sum[t]) - lse;
  }
}

extern "C" void kernel_launch(void* const* d_in, const int* in_sizes, int n_in,
                              void* d_out, int out_size, void* d_ws, size_t ws_size,
                              hipStream_t stream)
{
  const float* xq_num = (const float*)d_in[0];
  const float* xq_cat = (const float*)d_in[1];
  // d_in[2] = y (unused)
  const float* xc_num = (const float*)d_in[3];
  const float* xc_cat = (const float*)d_in[4];
  const int* cand_y = (const int*)d_in[5];
  const float* freq = (const float*)d_in[6];
  const float* lin_w = (const float*)d_in[7];
  const float* lin_b = (const float*)d_in[8];
  const float* enc_w = (const float*)d_in[9];
  const float* enc_b = (const float*)d_in[10];

  u16* h_bf = (u16*)d_ws;                                        // 41024*512 bf16
  float* norms = (float*)((char*)d_ws + (size_t)ROWS_TOT * DIM * 2);
  float* cls_part = norms + ROWS_TOT;                            // [320][1024][10]
  float* lse_part = cls_part + (size_t)NCT * BQ * NCLS;          // [320][1024]
  u16* enc_wT = (u16*)(lse_part + (size_t)NCT * BQ);             // [512][800]
  float* out = (float*)d_out;

  hipLaunchKernelGGL(k_prep, dim3((DIM * KDIM + 255) / 256), dim3(256), 0, stream,
                     enc_w, enc_wT);
  hipLaunchKernelGGL(k_encode, dim3(ROWS_TOT / 32), dim3(256), 0, stream,
                     xq_num, xq_cat, xc_num, xc_cat, freq, lin_w, lin_b,
                     enc_wT, enc_b, h_bf, norms);
  hipLaunchKernelGGL(k_dist, dim3(NCT, BQ / 64), dim3(256), 0, stream,
                     h_bf, norms, cand_y, cls_part, lse_part);
  hipLaunchKernelGGL(k_final, dim3(BQ), dim3(320), 0, stream,
                     cls_part, lse_part, out);
}